// Round 2
// baseline (302.133 us; speedup 1.0000x reference)
//
#include <hip/hip_runtime.h>

// x: (B=64, GS=96, C=8, C=8) float32
// out[b,i,j,c1,c2,k] : (B, 96, 96, 8, 8, 2) float32
//   k=0 -> x[b,i,c1,c2]   k=1 -> x[b,j,c1,c2]
// Pure broadcast: 1.5 MB read (L2-resident), 302 MB write -> write-BW bound
// (~48 us floor at 6.3 TB/s).
//
// R2: fill-mimicry. R1 showed store cache policy (nt vs plain) is neutral;
// kernel stuck at ~3 TB/s while rocclr fill hits 6.36 TB/s at ~3 waves/CU.
// Remaining structural deltas vs fill: (a) loads interleaved 1:1 with stores
// (every 12-store burst gated by an L2 load round-trip), (b) short-lived
// waves (12 stores then endpgm). Fix: long-lived waves with a pure store
// stream. Each thread preloads its 12 b-row float2 values ONCE into
// registers, then loops over 6 i-slabs: 1 prefetched a-load + 12
// back-to-back 1KB/wave stores per slab.

typedef float f32x4 __attribute__((ext_vector_type(4)));

constexpr int GS = 96;
constexpr int CC = 64;                      // C*C floats per (b,g) row
constexpr int F4_PER_J = 32;                // 8*8*2 floats / 4 per (i,j) tile
constexpr int F4_PER_SLAB = GS * F4_PER_J;  // 3072 float4 per (b,i) slab
constexpr int NI = 6;                       // i-slabs per block
constexpr int GX = GS / NI;                 // 16 blocks along i

__global__ __launch_bounds__(256)
void gcom_combo_kernel(const float* __restrict__ x, f32x4* __restrict__ out) {
    const int b  = blockIdx.y;
    const int i0 = blockIdx.x * NI;
    const int t  = threadIdx.x;

    // Fixed per-thread position within each (i,j) 32-float4 tile:
    const int q  = t & 31;        // 0..31
    const int jb = t >> 5;        // 0..7 : j residue class
    const int c1 = q >> 2;
    const int p  = q & 3;
    const int off = c1 * 8 + 2 * p;

    const float* xb = x + (size_t)b * (GS * CC);

    // Preload ALL b-row values this thread will ever need: j = jb + 8m.
    // 12 x float2 = 24 VGPRs, loop-invariant for the whole block lifetime.
    float2 bv[12];
    #pragma unroll
    for (int m = 0; m < 12; ++m)
        bv[m] = *(const float2*)(xb + (jb + 8 * m) * CC + off);

    // Software-pipelined a-load: fetch slab i's pair one iteration ahead.
    float2 a = *(const float2*)(xb + i0 * CC + off);

    #pragma unroll 1
    for (int ii = 0; ii < NI; ++ii) {
        const int i = i0 + ii;
        const int inext = (ii < NI - 1) ? (i + 1) : i;   // clamped prefetch
        float2 an = *(const float2*)(xb + inext * CC + off);

        f32x4* outSlab = out + (size_t)(b * GS + i) * F4_PER_SLAB;
        // Pure store burst: 12 independent 1KB/wave stores, no loads, no waits.
        #pragma unroll
        for (int m = 0; m < 12; ++m) {
            const int j = jb + 8 * m;
            // f32x4 covers (c2=2p,k=0),(2p,k=1),(2p+1,k=0),(2p+1,k=1)
            f32x4 v = { a.x, bv[m].x, a.y, bv[m].y };
            outSlab[j * F4_PER_J + q] = v;
        }
        a = an;
    }
}

extern "C" void kernel_launch(void* const* d_in, const int* in_sizes, int n_in,
                              void* d_out, int out_size, void* d_ws, size_t ws_size,
                              hipStream_t stream) {
    const float* x = (const float*)d_in[0];
    f32x4* out = (f32x4*)d_out;
    const int B = in_sizes[0] / (GS * CC);   // 64
    dim3 grid(GX, B);                        // 16 x 64 = 1024 blocks (4/CU)
    gcom_combo_kernel<<<grid, dim3(256), 0, stream>>>(x, out);
}